// Round 8
// baseline (208.497 us; speedup 1.0000x reference)
//
#include <hip/hip_runtime.h>
#include <hip/hip_bf16.h>

constexpr int N_NODES = 40000;
constexpr int N_EDGES = 640000;
constexpr int D = 128;
constexpr float BN_EPS = 1e-5f;
constexpr int SCAN_BLOCKS = 157;  // ceil(40000/256)
constexpr int NCOPY = 8;          // XCD-sharded counter copies

typedef __attribute__((ext_vector_type(8))) short short8;
typedef __attribute__((ext_vector_type(4))) float f32x4;

static_assert(N_EDGES == N_NODES * D / 8, "hist_cvt fusion assumes equal ranges");

__device__ __forceinline__ unsigned bf16_rne(float f) {
    unsigned b = __float_as_uint(f);
    return (b + 0x7FFFu + ((b >> 16) & 1u)) >> 16;
}
__device__ __forceinline__ float bflo(unsigned w) { return __uint_as_float(w << 16); }
__device__ __forceinline__ float bfhi(unsigned w) { return __uint_as_float(w & 0xFFFF0000u); }

// ---------------------------------------------------------------------------
// Kernel 1a: degree histogram (XCD-sharded: copy = blockIdx&7, so atomics
// stay within one XCD's L2 under round-robin dispatch — kills cross-XCD
// line ping-pong) + h -> bf16 + (first 4096 threads) W -> frag-major bf16.
// ---------------------------------------------------------------------------
__global__ void hist_cvt_kernel(const int* __restrict__ dst,
                                int* __restrict__ hist8,
                                const float4* __restrict__ h4,
                                uint4* __restrict__ hb4,
                                const float* __restrict__ Wself,
                                const float* __restrict__ Wneigh,
                                uint4* __restrict__ wfrag) {
    int e = blockIdx.x * blockDim.x + threadIdx.x;
    if (e >= N_EDGES) return;
    int c = blockIdx.x & (NCOPY - 1);
    atomicAdd(&hist8[c * N_NODES + dst[e]], 1);
    float4 a = h4[2 * e];
    float4 b = h4[2 * e + 1];
    uint4 o;
    o.x = bf16_rne(a.x) | (bf16_rne(a.y) << 16);
    o.y = bf16_rne(a.z) | (bf16_rne(a.w) << 16);
    o.z = bf16_rne(b.x) | (bf16_rne(b.y) << 16);
    o.w = bf16_rne(b.z) | (bf16_rne(b.w) << 16);
    hb4[e] = o;

    if (e < 4096) {
        int G = e;
        int l = G & 63;
        int tile = G >> 6;
        int kg = l >> 4;
        int n = l & 15;
        int ct = tile >> 3;
        int kt = tile & 7;
        int k0 = kt * 32 + kg * 8;
        int col = ct * 16 + n;
        unsigned w[8];
        #pragma unroll
        for (int j = 0; j < 8; j++) {
            int k = k0 + j;
            float v = (k < D) ? Wself[(size_t)k * D + col]
                              : Wneigh[(size_t)(k - D) * D + col];
            w[j] = bf16_rne(v);
        }
        uint4 ow;
        ow.x = w[0] | (w[1] << 16);
        ow.y = w[2] | (w[3] << 16);
        ow.z = w[4] | (w[5] << 16);
        ow.w = w[6] | (w[7] << 16);
        wfrag[G] = ow;
    }
}

// ---------------------------------------------------------------------------
// Scan phase 1: fold the 8 histogram copies per node -> deg_i[v], rewrite
// hist8[c][v] in place with the per-copy EXCLUSIVE prefix (so fill can
// compute exact slots with copy-local atomics), and emit per-block sums.
// ---------------------------------------------------------------------------
__global__ __launch_bounds__(256) void scan1_kernel(int* __restrict__ hist8,
                                                    int* __restrict__ deg_i,
                                                    int* __restrict__ partials) {
    __shared__ int sh[256];
    int t = threadIdx.x;
    int v = blockIdx.x * 256 + t;
    int deg = 0;
    if (v < N_NODES) {
        int run = 0;
        #pragma unroll
        for (int c = 0; c < NCOPY; c++) {
            int x = hist8[c * N_NODES + v];
            hist8[c * N_NODES + v] = run;
            run += x;
        }
        deg = run;
        deg_i[v] = deg;
    }
    sh[t] = deg;
    __syncthreads();
    for (int off = 128; off >= 1; off >>= 1) {
        if (t < off) sh[t] += sh[t + off];
        __syncthreads();
    }
    if (t == 0) partials[blockIdx.x] = sh[0];
}

// ---------------------------------------------------------------------------
// Scan phase 2+3 fused: block b reduces partials[0..b) for its offset, then
// locally scans its 256 deg values -> row_start. Last block writes total.
// ---------------------------------------------------------------------------
__global__ __launch_bounds__(256) void scan23_kernel(const int* __restrict__ deg_i,
                                                     const int* __restrict__ partials,
                                                     int* __restrict__ row_start) {
    __shared__ int sh[256];
    __shared__ int offs;
    int t = threadIdx.x;
    int b = blockIdx.x;
    sh[t] = (t < b) ? partials[t] : 0;   // b <= 156 < 256, safe
    __syncthreads();
    for (int off = 128; off >= 1; off >>= 1) {
        if (t < off) sh[t] += sh[t + off];
        __syncthreads();
    }
    if (t == 0) offs = sh[0];
    __syncthreads();
    int i = b * 256 + t;
    int v = (i < N_NODES) ? deg_i[i] : 0;
    sh[t] = v;
    __syncthreads();
    for (int off = 1; off < 256; off <<= 1) {
        int u = (t >= off) ? sh[t - off] : 0;
        __syncthreads();
        sh[t] += u;
        __syncthreads();
    }
    if (i < N_NODES) row_start[i] = sh[t] - v + offs;
    if (b == SCAN_BLOCKS - 1 && t == 255) row_start[N_NODES] = sh[255] + offs;
}

// ---------------------------------------------------------------------------
// Kernel 1c: bucket-fill with XCD-sharded cursors. Same grid/copy mapping as
// hist_cvt, so edge e's copy c matches its histogram count; slot =
// row_start[t] + copy_prefix (hist8[c][t]) + copy-local cursor tick.
// ---------------------------------------------------------------------------
__global__ void fill_kernel(const int* __restrict__ src,
                            const int* __restrict__ dst,
                            const int* __restrict__ row_start,
                            const int* __restrict__ hist8,
                            int* __restrict__ cur8,
                            int* __restrict__ esrc) {
    int e = blockIdx.x * blockDim.x + threadIdx.x;
    if (e >= N_EDGES) return;
    int c = blockIdx.x & (NCOPY - 1);
    int t = dst[e];
    int p = atomicAdd(&cur8[c * N_NODES + t], 1);
    esrc[row_start[t] + hist8[c * N_NODES + t] + p] = src[e];
}

// ---------------------------------------------------------------------------
// Kernel 1d: gather + mean, one wave per node (4 edge-slots x 16 granules).
// ---------------------------------------------------------------------------
__global__ __launch_bounds__(256) void gather_kernel(
        const uint4* __restrict__ hb4,
        const int* __restrict__ row_start,
        const int* __restrict__ esrc,
        uint4* __restrict__ hnb4) {
    int node = (blockIdx.x * blockDim.x + threadIdx.x) >> 6;
    int lane = threadIdx.x & 63;
    if (node >= N_NODES) return;
    int g  = lane & 15;   // granule within row
    int es = lane >> 4;   // edge slot 0..3
    int s0 = row_start[node];
    int s1 = row_start[node + 1];
    float acc[8] = {0.f, 0.f, 0.f, 0.f, 0.f, 0.f, 0.f, 0.f};
    for (int j = s0 + es; j < s1; j += 4) {
        int a = esrc[j];
        uint4 v = hb4[(size_t)a * 16 + g];
        acc[0] += bflo(v.x); acc[1] += bfhi(v.x);
        acc[2] += bflo(v.y); acc[3] += bfhi(v.y);
        acc[4] += bflo(v.z); acc[5] += bfhi(v.z);
        acc[6] += bflo(v.w); acc[7] += bfhi(v.w);
    }
    #pragma unroll
    for (int i = 0; i < 8; i++) {
        acc[i] += __shfl_xor(acc[i], 16);
        acc[i] += __shfl_xor(acc[i], 32);
    }
    if (es == 0) {
        int len = s1 - s0;
        float rd = 1.0f / (float)(len > 1 ? len : 1);
        uint4 o;
        o.x = bf16_rne(acc[0] * rd) | (bf16_rne(acc[1] * rd) << 16);
        o.y = bf16_rne(acc[2] * rd) | (bf16_rne(acc[3] * rd) << 16);
        o.z = bf16_rne(acc[4] * rd) | (bf16_rne(acc[5] * rd) << 16);
        o.w = bf16_rne(acc[6] * rd) | (bf16_rne(acc[7] * rd) << 16);
        hnb4[(size_t)node * 16 + g] = o;
    }
}

// ---------------------------------------------------------------------------
// Kernel 2: MFMA dual GEMM. Grid = 625 rowtiles x 2 colhalves, block = 256
// threads (4 waves) = 64 rows x 64 cols. W staged frag-major into LDS (32KB),
// conflict-free ds_read_b128; 8 global A loads per wave; 32 MFMAs per wave.
// pre stored f32 into d_out.
// A[m=lane&15][k=(lane>>4)*8+j]; C/D: col=lane&15, row=(lane>>4)*4+reg.
// ---------------------------------------------------------------------------
__global__ __launch_bounds__(256) void gemm_mfma_kernel(
        const uint4* __restrict__ hb4,      // bf16 h, 16 granules/row
        const uint4* __restrict__ hnb4,     // bf16 hn, 16 granules/row
        const uint4* __restrict__ wfrag,    // frag-major bf16 W, 4096 granules
        const float* __restrict__ snorm,
        const float* __restrict__ bias,
        float* __restrict__ pre,            // f32 pre = d_out, [N][D]
        float* __restrict__ sums,
        float* __restrict__ sumsq) {
    __shared__ uint4 ldsW[2048];            // 32 KB: this col-half's 4 coltiles
    __shared__ float sums_l[64];
    __shared__ float sumsq_l[64];

    int t = threadIdx.x;
    int lane = t & 63;
    int wid = t >> 6;
    int n = lane & 15;
    int kg = lane >> 4;
    int rowtile = blockIdx.x >> 1;
    int cbt = blockIdx.x & 1;
    int cb = cbt * 64;
    int row_base = rowtile * 64 + wid * 16;
    int row = row_base + n;

    if (t < 64) { sums_l[t] = 0.f; sumsq_l[t] = 0.f; }

    short8 a[8];
    #pragma unroll
    for (int kt = 0; kt < 4; kt++) {
        uint4 v = hb4[(size_t)row * 16 + kt * 4 + kg];
        a[kt] = __builtin_bit_cast(short8, v);
    }
    #pragma unroll
    for (int kt = 0; kt < 4; kt++) {
        uint4 v = hnb4[(size_t)row * 16 + kt * 4 + kg];
        a[4 + kt] = __builtin_bit_cast(short8, v);
    }

    #pragma unroll
    for (int i = 0; i < 8; i++) {
        int g = i * 256 + t;
        ldsW[g] = wfrag[cbt * 2048 + g];
    }
    __syncthreads();

    f32x4 acc[4];
    #pragma unroll
    for (int lt = 0; lt < 4; lt++) acc[lt] = (f32x4){0.f, 0.f, 0.f, 0.f};

    #pragma unroll
    for (int lt = 0; lt < 4; lt++) {
        #pragma unroll
        for (int kt = 0; kt < 8; kt++) {
            short8 b = __builtin_bit_cast(short8, ldsW[(lt * 8 + kt) * 64 + lane]);
            acc[lt] = __builtin_amdgcn_mfma_f32_16x16x32_bf16(a[kt], b, acc[lt], 0, 0, 0);
        }
    }

    float snv[4];
    #pragma unroll
    for (int r = 0; r < 4; r++) snv[r] = snorm[row_base + kg * 4 + r];

    #pragma unroll
    for (int lt = 0; lt < 4; lt++) {
        int col = cb + lt * 16 + n;
        float bb = bias[col];
        float csum = 0.f, csq = 0.f;
        #pragma unroll
        for (int r = 0; r < 4; r++) {
            int rr = row_base + kg * 4 + r;
            float v = acc[lt][r] + bb;
            v = fmaxf(v, 0.f);
            v *= snv[r];
            pre[(size_t)rr * D + col] = v;
            csum += v;
            csq += v * v;
        }
        csum += __shfl_xor(csum, 16); csq += __shfl_xor(csq, 16);
        csum += __shfl_xor(csum, 32); csq += __shfl_xor(csq, 32);
        if (kg == 0) {
            atomicAdd(&sums_l[lt * 16 + n], csum);
            atomicAdd(&sumsq_l[lt * 16 + n], csq);
        }
    }
    __syncthreads();
    if (t < 64) {
        atomicAdd(&sums[cb + t], sums_l[t]);
        atomicAdd(&sumsq[cb + t], sumsq_l[t]);
    }
}

// ---------------------------------------------------------------------------
// Kernel 3: finalize in place on d_out: out = h + (pre - mean)*scale + beta.
// ---------------------------------------------------------------------------
__global__ void final_kernel(const float4* __restrict__ h4,
                             const float4* __restrict__ sums4,
                             const float4* __restrict__ sumsq4,
                             const float4* __restrict__ gamma4,
                             const float4* __restrict__ beta4,
                             float4* __restrict__ out4) {
    int idx = blockIdx.x * blockDim.x + threadIdx.x;  // over N*D/4
    int total = N_NODES * D / 4;
    if (idx >= total) return;
    int d4 = idx & 31;
    float4 s  = sums4[d4];
    float4 sq = sumsq4[d4];
    float4 g  = gamma4[d4];
    float4 bt = beta4[d4];
    const float invN = 1.0f / (float)N_NODES;
    float4 hv = h4[idx];
    float4 ov = out4[idx];
    float m, var, sc;
    m = s.x * invN; var = sq.x * invN - m * m; sc = g.x * rsqrtf(var + BN_EPS);
    ov.x = hv.x + (ov.x - m) * sc + bt.x;
    m = s.y * invN; var = sq.y * invN - m * m; sc = g.y * rsqrtf(var + BN_EPS);
    ov.y = hv.y + (ov.y - m) * sc + bt.y;
    m = s.z * invN; var = sq.z * invN - m * m; sc = g.z * rsqrtf(var + BN_EPS);
    ov.z = hv.z + (ov.z - m) * sc + bt.z;
    m = s.w * invN; var = sq.w * invN - m * m; sc = g.w * rsqrtf(var + BN_EPS);
    ov.w = hv.w + (ov.w - m) * sc + bt.w;
    out4[idx] = ov;
}

// ---------------------------------------------------------------------------
extern "C" void kernel_launch(void* const* d_in, const int* in_sizes, int n_in,
                              void* d_out, int out_size, void* d_ws, size_t ws_size,
                              hipStream_t stream) {
    const float* h      = (const float*)d_in[0];
    const float* snorm  = (const float*)d_in[1];
    const float* Wself  = (const float*)d_in[2];
    const float* Wneigh = (const float*)d_in[3];
    const float* bias   = (const float*)d_in[4];
    const float* gamma  = (const float*)d_in[5];
    const float* beta   = (const float*)d_in[6];
    const int*   src    = (const int*)d_in[7];
    const int*   dst    = (const int*)d_in[8];
    float* out = (float*)d_out;

    // ws layout:
    // zeroed:   [ hist8 : 8N int ][ cur8 : 8N int ][ sums : D f ][ sumsq : D f ]
    // unzeroed: [ deg_i : N ][ row_start : N+1 ][ partials : 160 ][ esrc : E ]
    //           [ wfrag : 64KB ][ hb : 10.2MB ][ hnb : 10.2MB ]
    int*   hist8     = (int*)d_ws;
    int*   cur8      = hist8 + NCOPY * N_NODES;
    float* sums      = (float*)(cur8 + NCOPY * N_NODES);
    float* sumsq     = sums + D;
    int*   deg_i     = (int*)(sumsq + D);
    int*   row_start = deg_i + N_NODES;
    int*   partials  = row_start + (N_NODES + 1);
    int*   esrc      = partials + 160;
    size_t off       = (size_t)((char*)(esrc + N_EDGES) - (char*)d_ws);
    off = (off + 15) & ~(size_t)15;
    uint4* wfrag = (uint4*)((char*)d_ws + off);
    uint4* hb4   = wfrag + 4096;
    uint4* hnb4  = hb4 + N_NODES * (D / 8);

    size_t zero_bytes = (size_t)(2 * NCOPY * N_NODES + 2 * D) * sizeof(float);
    hipMemsetAsync(d_ws, 0, zero_bytes, stream);

    // 1a) sharded histogram + h -> bf16 + W -> frag-major bf16
    hist_cvt_kernel<<<N_EDGES / 256, 256, 0, stream>>>(
        dst, hist8, (const float4*)h, hb4, Wself, Wneigh, wfrag);
    // 1b) scan: fold copies -> deg + per-copy prefixes; then row_start
    scan1_kernel<<<SCAN_BLOCKS, 256, 0, stream>>>(hist8, deg_i, partials);
    scan23_kernel<<<SCAN_BLOCKS, 256, 0, stream>>>(deg_i, partials, row_start);
    // 1c) bucket fill with copy-local cursors
    fill_kernel<<<N_EDGES / 256, 256, 0, stream>>>(
        src, dst, row_start, hist8, cur8, esrc);
    // 1d) gather + mean -> hnb (bf16), one wave per node
    gather_kernel<<<N_NODES / 4, 256, 0, stream>>>(hb4, row_start, esrc, hnb4);
    // 2) MFMA dual GEMM + relu + snorm + BN partials -> pre f32 (d_out)
    gemm_mfma_kernel<<<(N_NODES / 64) * 2, 256, 0, stream>>>(
        hb4, hnb4, wfrag, snorm, bias, out, sums, sumsq);
    // 3) finalize: residual + BN (in place on d_out)
    final_kernel<<<(N_NODES * D / 4) / 256, 256, 0, stream>>>(
        (const float4*)h, (const float4*)sums, (const float4*)sumsq,
        (const float4*)gamma, (const float4*)beta, (float4*)out);
}